// Round 2
// baseline (12305.634 us; speedup 1.0000x reference)
//
#include <hip/hip_runtime.h>
#include <hip/hip_bf16.h>

// GPT fwd: B=4,T=1024,C=1024,H=16,Hd=64,L=4(shared weights),V=32000
// Inputs are FLOAT32 (per reference dtypes); output f32. Internals use bf16 MFMA
// with an f32 residual master. Quirk: k=x@wk(in3), v=x@wq(in4), q=x@wv(in5).

using bf16 = __hip_bfloat16;
typedef __bf16 bf16x8 __attribute__((ext_vector_type(8)));
typedef float f32x4 __attribute__((ext_vector_type(4)));

#define TOK 4096      // B*T
#define C 1024
#define NH 16
#define HD 64
#define TT 1024
#define FF 4096
#define VOC 32000

__device__ inline float b2f(unsigned short u) {
    union { unsigned int i; float f; } v; v.i = ((unsigned int)u) << 16; return v.f;
}

// ---------------------------------------------------------------- embed
__global__ __launch_bounds__(256) void embed_kernel(
    const int* __restrict__ idx, const float* __restrict__ tok,
    const float* __restrict__ pos, float* __restrict__ xf, bf16* __restrict__ xb)
{
    int i = blockIdx.x * 256 + threadIdx.x;      // over TOK*C
    int t = i >> 10;            // token index 0..4095
    int c = i & 1023;
    int ti = t & 1023;          // position within sequence
    int v = idx[t];
    float val = tok[(size_t)v * C + c] + pos[(size_t)ti * C + c];
    xf[i] = val;
    xb[i] = (bf16)val;
}

// ---------------------------------------------------------------- GEMM
// C[M,N] (+)= A[M,K] @ B.  A is bf16 (internal). B is f32 (original input weight),
// converted to bf16 during LDS staging.
// BT=0: B is KxN row-major. BT=1: B given as B^T (NxK row-major).
// EPI: 0 = store bf16 to Cb; 1 = relu + store bf16; 2 = Xf += acc, Cb=bf16(Xf);
//      3 = store f32 to Cf.
// 64x64 tile, BK=64, 4 waves, mfma_f32_16x16x32_bf16.
// Fragment layouts (guide §3): A/B operand [idx16=lane&15][k=(lane>>4)*8+j];
// C/D: col = lane&15, row = (lane>>4)*4 + reg.
template <int BT, int EPI>
__global__ __launch_bounds__(256) void gemm_kernel(
    const bf16* __restrict__ A, const float* __restrict__ B,
    bf16* __restrict__ Cb, float* __restrict__ Cf, float* __restrict__ Xf,
    int M, int N, int K)
{
    __shared__ __align__(16) bf16 As[64][72];   // 72: 16B-aligned rows, breaks bank stride
    __shared__ __align__(16) bf16 Bs[64][72];   // stored [n][k]
    const int tid = threadIdx.x;
    const int lane = tid & 63;
    const int wave = tid >> 6;
    const int bm = blockIdx.y * 64;
    const int bn = blockIdx.x * 64;

    f32x4 acc[4] = {};

    const int r_st = tid >> 2;            // staging row 0..63
    const int c_st = (tid & 3) << 4;      // staging col 0,16,32,48

    for (int kc = 0; kc < K; kc += 64) {
        // stage A (bf16, M-major, contiguous K): 16 bf16 per thread, coalesced
        {
            const uint4* src = reinterpret_cast<const uint4*>(A + (size_t)(bm + r_st) * K + kc + c_st);
            uint4* dst = reinterpret_cast<uint4*>(&As[r_st][c_st]);
            dst[0] = src[0];
            dst[1] = src[1];
        }
        if (BT) {  // B^T given (NxK f32): rows are N, contiguous K; convert f32->bf16
            const float4* src = reinterpret_cast<const float4*>(B + (size_t)(bn + r_st) * K + kc + c_st);
            #pragma unroll
            for (int j = 0; j < 4; j++) {
                float4 f = src[j];
                int cc = c_st + 4 * j;
                Bs[r_st][cc + 0] = (bf16)f.x;
                Bs[r_st][cc + 1] = (bf16)f.y;
                Bs[r_st][cc + 2] = (bf16)f.z;
                Bs[r_st][cc + 3] = (bf16)f.w;
            }
        } else {   // B is KxN f32: transpose during staging (reads coalesced over n)
            #pragma unroll
            for (int i = 0; i < 16; i++) {
                int linear = tid + 256 * i;      // 0..4095
                int k = linear >> 6;
                int n = linear & 63;
                Bs[n][k] = (bf16)B[(size_t)(kc + k) * N + bn + n];
            }
        }
        __syncthreads();

        const int m16 = lane & 15;
        const int koff = (lane >> 4) * 8;
        #pragma unroll
        for (int ks = 0; ks < 64; ks += 32) {
            bf16x8 a = *reinterpret_cast<const bf16x8*>(&As[16 * wave + m16][ks + koff]);
            #pragma unroll
            for (int nt = 0; nt < 4; nt++) {
                bf16x8 b = *reinterpret_cast<const bf16x8*>(&Bs[16 * nt + m16][ks + koff]);
                acc[nt] = __builtin_amdgcn_mfma_f32_16x16x32_bf16(a, b, acc[nt], 0, 0, 0);
            }
        }
        __syncthreads();
    }

    // epilogue
    const int col0 = bn + (lane & 15);
    const int row0 = bm + 16 * wave + (lane >> 4) * 4;
    #pragma unroll
    for (int nt = 0; nt < 4; nt++) {
        int col = col0 + 16 * nt;
        #pragma unroll
        for (int r = 0; r < 4; r++) {
            size_t off = (size_t)(row0 + r) * N + col;
            float v = acc[nt][r];
            if (EPI == 0) {
                Cb[off] = (bf16)v;
            } else if (EPI == 1) {
                Cb[off] = (bf16)fmaxf(v, 0.f);
            } else if (EPI == 2) {
                float xn = Xf[off] + v;
                Xf[off] = xn;
                Cb[off] = (bf16)xn;
            } else {
                Cf[off] = v;
            }
        }
    }
}

// ---------------------------------------------------------------- attention
// One block (256 thr) per (b, head, query-row). Two-phase: scores+softmax in LDS, then PV.
__global__ __launch_bounds__(256) void attn_kernel(
    const bf16* __restrict__ qb, const bf16* __restrict__ kb,
    const bf16* __restrict__ vb, bf16* __restrict__ ob)
{
    const int qi = blockIdx.x;
    const int n  = blockIdx.y;
    const int b  = blockIdx.z;
    const int tid = threadIdx.x;
    const int t0 = b * TT;

    __shared__ float qs[HD];
    __shared__ float s[TT];
    __shared__ float red[256];

    const bf16* qrow = qb + (size_t)(t0 + qi) * C + n * HD;
    if (tid < HD) qs[tid] = (float)qrow[tid];
    __syncthreads();

    // phase 1: scores (masked)
    typedef unsigned short us8 __attribute__((ext_vector_type(8)));
    for (int k = tid; k < TT; k += 256) {
        float d = -1e30f;
        if (k <= qi) {
            const us8* kr = reinterpret_cast<const us8*>(kb + (size_t)(t0 + k) * C + n * HD);
            float acc = 0.f;
            #pragma unroll
            for (int j = 0; j < 8; j++) {
                us8 kv = kr[j];
                #pragma unroll
                for (int e = 0; e < 8; e++) acc += qs[j * 8 + e] * b2f(kv[e]);
            }
            d = acc * 0.125f;   // 1/sqrt(64)
        }
        s[k] = d;
    }
    __syncthreads();

    // softmax: max
    float m = -1e30f;
    for (int k = tid; k < TT; k += 256) m = fmaxf(m, s[k]);
    red[tid] = m; __syncthreads();
    for (int off = 128; off > 0; off >>= 1) {
        if (tid < off) red[tid] = fmaxf(red[tid], red[tid + off]);
        __syncthreads();
    }
    m = red[0]; __syncthreads();

    // exp + sum
    float sum = 0.f;
    for (int k = tid; k < TT; k += 256) {
        float p = __expf(s[k] - m);
        if (k > qi) p = 0.f;
        s[k] = p;
        sum += p;
    }
    red[tid] = sum; __syncthreads();
    for (int off = 128; off > 0; off >>= 1) {
        if (tid < off) red[tid] += red[tid + off];
        __syncthreads();
    }
    float inv = 1.0f / red[0];
    __syncthreads();   // protect red before reuse

    // phase 2: o[h] = sum_k p[k] * v[k][h]; h = tid&63, key-chunk = tid>>6
    const int h = tid & 63;
    const int ch = tid >> 6;
    const int kend = min((ch + 1) * 256, qi + 1);
    float acc = 0.f;
    for (int k = ch * 256; k < kend; k++) {
        acc += s[k] * (float)vb[(size_t)(t0 + k) * C + n * HD + h];
    }
    red[tid] = acc * inv;
    __syncthreads();
    if (tid < 64) {
        float o = red[tid] + red[tid + 64] + red[tid + 128] + red[tid + 192];
        ob[(size_t)(t0 + qi) * C + n * HD + tid] = (bf16)o;
    }
}

// ---------------------------------------------------------------- launch
extern "C" void kernel_launch(void* const* d_in, const int* in_sizes, int n_in,
                              void* d_out, int out_size, void* d_ws, size_t ws_size,
                              hipStream_t stream) {
    const int*   idx    = (const int*)  d_in[0];
    const float* tok    = (const float*)d_in[1];
    const float* pos    = (const float*)d_in[2];
    const float* wk     = (const float*)d_in[3];
    const float* wq     = (const float*)d_in[4];
    const float* wv     = (const float*)d_in[5];
    const float* w_proj = (const float*)d_in[6];
    const float* w_in   = (const float*)d_in[7];
    const float* w_out  = (const float*)d_in[8];
    float* out = (float*)d_out;

    char* w = (char*)d_ws;
    float* xf = (float*)w;            w += (size_t)TOK * C * 4;   // 16 MB f32 master
    bf16* xb = (bf16*)w;              w += (size_t)TOK * C * 2;   // 8 MB
    bf16* kbuf = (bf16*)w;            w += (size_t)TOK * C * 2;
    bf16* vbuf = (bf16*)w;            w += (size_t)TOK * C * 2;
    bf16* qbuf = (bf16*)w;            w += (size_t)TOK * C * 2;
    bf16* obuf = (bf16*)w;            w += (size_t)TOK * C * 2;
    bf16* hbuf = (bf16*)w;            w += (size_t)TOK * FF * 2;  // 32 MB

    embed_kernel<<<TOK * C / 256, 256, 0, stream>>>(idx, tok, pos, xf, xb);

    dim3 gC(C / 64, TOK / 64);     // N=1024 GEMMs
    dim3 gF(FF / 64, TOK / 64);    // N=4096 GEMM
    dim3 gV(VOC / 64, TOK / 64);   // logits

    for (int layer = 0; layer < 4; layer++) {
        // reference quirk: k<-wk, v<-wq, q<-wv
        gemm_kernel<0, 0><<<gC, 256, 0, stream>>>(xb, wk, kbuf, nullptr, nullptr, TOK, C, C);
        gemm_kernel<0, 0><<<gC, 256, 0, stream>>>(xb, wq, vbuf, nullptr, nullptr, TOK, C, C);
        gemm_kernel<0, 0><<<gC, 256, 0, stream>>>(xb, wv, qbuf, nullptr, nullptr, TOK, C, C);

        attn_kernel<<<dim3(TT, NH, 4), 256, 0, stream>>>(qbuf, kbuf, vbuf, obuf);

        // x += o @ w_proj^T  (w_proj rows are output-c, contiguous K=(n,h) -> NT)
        gemm_kernel<1, 2><<<gC, 256, 0, stream>>>(obuf, w_proj, xb, nullptr, xf, TOK, C, C);

        // h = relu(x @ w_in)  (w_in KxN row-major -> NN)
        gemm_kernel<0, 1><<<gF, 256, 0, stream>>>(xb, w_in, hbuf, nullptr, nullptr, TOK, FF, C);
        // x += h @ w_out
        gemm_kernel<0, 2><<<gC, 256, 0, stream>>>(hbuf, w_out, xb, nullptr, xf, TOK, C, FF);
    }

    // logits = x @ token_emb^T  (token_emb rows are vocab, contiguous K=C -> NT), f32 out
    gemm_kernel<1, 3><<<gV, 256, 0, stream>>>(xb, tok, nullptr, out, nullptr, TOK, VOC, C);
}